// Round 5
// baseline (242.165 us; speedup 1.0000x reference)
//
#include <hip/hip_runtime.h>
#include <hip/hip_bf16.h>

#define C_DIM 100000
#define NROW 512
#define DDIM 512
#define BN 64
#define NPANEL 1563            // ceil(C_DIM/BN)
#define PANEL_ELEMS 32768      // 64 cols x 512 k (bf16)

typedef __attribute__((ext_vector_type(4))) float f32x4;
typedef __attribute__((ext_vector_type(8))) short bf16x8;
typedef __attribute__((ext_vector_type(4))) float f32acc;

// ---------------- kernel 1: inv row norms of W (norm over C per row d) ----------
__global__ __launch_bounds__(256) void cf_knorm(const float* __restrict__ W,
                                                float* __restrict__ inv_norm) {
    const int d = blockIdx.x;
    const float* row = W + (size_t)d * C_DIM;
    float s = 0.f;
    for (int c4 = threadIdx.x; c4 < C_DIM / 4; c4 += 256) {
        f32x4 v = *(const f32x4*)(row + c4 * 4);
        s += v.x * v.x + v.y * v.y + v.z * v.z + v.w * v.w;
    }
    #pragma unroll
    for (int off = 32; off; off >>= 1) s += __shfl_down(s, off, 64);
    __shared__ float wsum[4];
    if ((threadIdx.x & 63) == 0) wsum[threadIdx.x >> 6] = s;
    __syncthreads();
    if (threadIdx.x == 0) {
        float t = wsum[0] + wsum[1] + wsum[2] + wsum[3];
        inv_norm[d] = 1.0f / sqrtf(t);
    }
}

// ---- kernel 1b: Wt = bf16(W * inv_norm[k]) as pre-swizzled 64KB panel images ----
// Panel p, col c (0..63), k: element at p*32768 + c*512 + (((k>>3)^(c&7))*8 + (k&7)).
// Staged via LDS exactly like the GEMM's staging, then dumped linearly (coalesced).
__global__ __launch_bounds__(512) void cf_kconv(const float* __restrict__ W,
                                                const float* __restrict__ inv_norm,
                                                __hip_bfloat16* __restrict__ Wt) {
    __shared__ __attribute__((aligned(16))) __hip_bfloat16 Bl[64 * 512];
    const int tid = threadIdx.x;
    const int cb  = blockIdx.x * BN;
    const int c4  = (tid & 15) * 4;
    const int k8  = tid >> 4;            // 0..31
    const bool ok = (cb + c4) < C_DIM;
    #pragma unroll
    for (int kk2 = 0; kk2 < 2; ++kk2) {
        const int kb = kk2 * 256 + k8 * 8;
        f32x4 v[8];
        #pragma unroll
        for (int j = 0; j < 8; ++j) {
            if (ok) v[j] = *(const f32x4*)(W + (size_t)(kb + j) * C_DIM + cb + c4);
            else    v[j] = (f32x4){0.f, 0.f, 0.f, 0.f};
            const float sc = inv_norm[kb + j];
            v[j].x *= sc; v[j].y *= sc; v[j].z *= sc; v[j].w *= sc;
        }
        const int q = kk2 * 32 + k8;
        #pragma unroll
        for (int cc = 0; cc < 4; ++cc) {
            const int c = c4 + cc;
            union { __hip_bfloat16 h[8]; bf16x8 b; } p;
            #pragma unroll
            for (int j = 0; j < 8; ++j) p.h[j] = __float2bfloat16(v[j][cc]);
            *(bf16x8*)&Bl[c * 512 + (q ^ (c & 7)) * 8] = p.b;
        }
    }
    __syncthreads();
    __hip_bfloat16* dst = Wt + (size_t)blockIdx.x * PANEL_ELEMS;
    #pragma unroll
    for (int i = 0; i < 8; ++i)
        *(bf16x8*)(dst + i * 4096 + tid * 8) = *(const bf16x8*)&Bl[i * 4096 + tid * 8];
}

// ------- kernel 2: xs2 = bf16(x [* inv_norm]) in MFMA-fragment-tiled layout -----
// xs2[((row>>4)*64 + k8)*128 + (row&15)*8 + e]  (row=0..511, col=k8*8+e)
__global__ __launch_bounds__(256) void cf_kxs2(const float* __restrict__ x,
                                               const float* __restrict__ inv_norm,
                                               __hip_bfloat16* __restrict__ xs2,
                                               int do_scale) {
    const int idx = blockIdx.x * 256 + threadIdx.x;   // 0..32767
    const int row = idx >> 6;
    const int k8  = idx & 63;
    const float* xp = x + (size_t)row * DDIM + k8 * 8;
    f32x4 v0 = *(const f32x4*)(xp);
    f32x4 v1 = *(const f32x4*)(xp + 4);
    if (do_scale) {
        f32x4 s0 = *(const f32x4*)(inv_norm + k8 * 8);
        f32x4 s1 = *(const f32x4*)(inv_norm + k8 * 8 + 4);
        #pragma unroll
        for (int e = 0; e < 4; ++e) { v0[e] *= s0[e]; v1[e] *= s1[e]; }
    }
    union { __hip_bfloat16 h[8]; bf16x8 v; } p;
    #pragma unroll
    for (int e = 0; e < 4; ++e) p.h[e]     = __float2bfloat16(v0[e]);
    #pragma unroll
    for (int e = 0; e < 4; ++e) p.h[4 + e] = __float2bfloat16(v1[e]);
    *(bf16x8*)(xs2 + ((size_t)((row >> 4) * 64 + k8) * 128 + (row & 15) * 8)) = p.v;
}

// ---------------- kernel 3: target logits, cos_m, final -------------------------
__global__ __launch_bounds__(64) void cf_ktgt(const float* __restrict__ x,
                                              const float* __restrict__ W,
                                              const float* __restrict__ inv_norm,
                                              const int* __restrict__ label,
                                              float* __restrict__ tl,
                                              float* __restrict__ cm,
                                              float* __restrict__ fl) {
    const int i = blockIdx.x;
    const int lane = threadIdx.x;
    const int lab = label[i];
    float s = 0.f;
    for (int d = lane; d < DDIM; d += 64)
        s += x[(size_t)i * DDIM + d] * inv_norm[d] * W[(size_t)d * C_DIM + lab];
    #pragma unroll
    for (int off = 32; off; off >>= 1) s += __shfl_down(s, off, 64);
    if (lane == 0) {
        float t = fminf(fmaxf(s, -1.f), 1.f);
        float sn = sqrtf(fmaxf(1.f - t * t, 0.f));
        float c = t * 0.8775825618903728f - sn * 0.479425538604203f; // cos(th+m)
        tl[i] = t;
        cm[i] = c;
        fl[i] = (t > -0.8775825618903728f) ? c : (t - 0.2397127693021015f);
    }
}

// ---------------- kernel 4: t = 0.01 * mean(target_logit) -----------------------
__global__ __launch_bounds__(512) void cf_kt(const float* __restrict__ tl,
                                             float* __restrict__ tout) {
    float s = tl[threadIdx.x];
    #pragma unroll
    for (int off = 32; off; off >>= 1) s += __shfl_down(s, off, 64);
    __shared__ float w[8];
    if ((threadIdx.x & 63) == 0) w[threadIdx.x >> 6] = s;
    __syncthreads();
    if (threadIdx.x == 0) {
        float tt = 0.f;
        #pragma unroll
        for (int j = 0; j < 8; ++j) tt += w[j];
        tout[0] = 0.01f * (tt / 512.0f);
    }
}

// ------------- shared epilogue (D[c][i] acc -> curricular logits) ---------------
__device__ __forceinline__ void cf_epilogue(f32acc (&acc)[4][4], int wv, int il,
                                            int hi, int cb,
                                            const int* __restrict__ label,
                                            const float* __restrict__ cosm,
                                            const float* __restrict__ finl,
                                            float t, float* __restrict__ out) {
    const int ib = wv * 64;
    #pragma unroll
    for (int n = 0; n < 4; ++n) {
        const int i = ib + n * 16 + il;
        const float cmv = cosm[i];
        const float flv = finl[i];
        const int lab = label[i];
        float* orow = out + (size_t)i * C_DIM;
        #pragma unroll
        for (int m = 0; m < 4; ++m) {
            const int c0 = cb + m * 16 + hi * 4;
            if (c0 < C_DIM) {
                f32x4 v = acc[m][n];
                f32x4 o;
                #pragma unroll
                for (int r = 0; r < 4; ++r) {
                    float cz = fminf(fmaxf(v[r], -1.f), 1.f);
                    float ov = (cz > cmv) ? cz * (t + cz) : cz;
                    if (c0 + r == lab) ov = flv;
                    o[r] = ov * 64.0f;
                }
                *(f32x4*)(orow + c0) = o;
            }
        }
    }
}

// ------------- kernel 5a: GEMM from pre-converted bf16 panels (fast path) -------
__global__ __launch_bounds__(512, 4) void cf_kgemm2(
    const __hip_bfloat16* __restrict__ xs2,
    const __hip_bfloat16* __restrict__ Wt,
    const int* __restrict__ label,
    const float* __restrict__ cosm,
    const float* __restrict__ finl,
    const float* __restrict__ tp,
    float* __restrict__ out) {
    __shared__ __attribute__((aligned(16))) __hip_bfloat16 Bl[64 * 512];

    const int tid  = threadIdx.x;
    const int wv   = tid >> 6;
    const int lane = tid & 63;
    const int il   = lane & 15;
    const int hi   = lane >> 4;
    const int cb   = blockIdx.x * BN;

    // ---- stage: pure linear copy of the pre-swizzled 64KB panel image ----
    {
        const __hip_bfloat16* src = Wt + (size_t)blockIdx.x * PANEL_ELEMS;
        bf16x8 r[8];
        #pragma unroll
        for (int i = 0; i < 8; ++i)
            r[i] = *(const bf16x8*)(src + i * 4096 + tid * 8);
        #pragma unroll
        for (int i = 0; i < 8; ++i)
            *(bf16x8*)&Bl[i * 4096 + tid * 8] = r[i];
    }
    __syncthreads();

    f32acc acc[4][4];
    #pragma unroll
    for (int m = 0; m < 4; ++m)
        #pragma unroll
        for (int n = 0; n < 4; ++n)
            acc[m][n] = (f32acc){0.f, 0.f, 0.f, 0.f};

    int crow[4];
    #pragma unroll
    for (int m = 0; m < 4; ++m) crow[m] = (m * 16 + il) * 512;

    auto loadB = [&](bf16x8 (&bb)[4], int kt) {
        #pragma unroll
        for (int n = 0; n < 4; ++n)
            bb[n] = *(const bf16x8*)(xs2 + (size_t)((wv * 4 + n) * 64 + kt * 4 + hi) * 128 + il * 8);
    };
    auto step = [&](const bf16x8 (&bb)[4], int kt) {
        bf16x8 a[4];
        #pragma unroll
        for (int m = 0; m < 4; ++m) {
            const int c = m * 16 + il;
            const int q = (kt * 4 + hi) ^ (c & 7);
            a[m] = *(const bf16x8*)&Bl[crow[m] + q * 8];
        }
        #pragma unroll
        for (int m = 0; m < 4; ++m)
            #pragma unroll
            for (int n = 0; n < 4; ++n)
                acc[m][n] = __builtin_amdgcn_mfma_f32_16x16x32_bf16(a[m], bb[n], acc[m][n], 0, 0, 0);
    };

    bf16x8 b0[4], b1[4];
    loadB(b0, 0);
    #pragma unroll
    for (int kt = 0; kt < 16; kt += 2) {
        if (kt + 1 < 16) loadB(b1, kt + 1);
        step(b0, kt);
        if (kt + 2 < 16) loadB(b0, kt + 2);
        if (kt + 1 < 16) step(b1, kt + 1);
    }

    cf_epilogue(acc, wv, il, hi, cb, label, cosm, finl, tp[0], out);
}

// ------------- kernel 5b: GEMM staging W f32 directly (fallback path) -----------
__global__ __launch_bounds__(512, 4) void cf_kgemm(
    const __hip_bfloat16* __restrict__ xs2,
    const float* __restrict__ W,
    const int* __restrict__ label,
    const float* __restrict__ cosm,
    const float* __restrict__ finl,
    const float* __restrict__ tp,
    float* __restrict__ out) {
    __shared__ __attribute__((aligned(16))) __hip_bfloat16 Bl[64 * 512];

    const int tid  = threadIdx.x;
    const int wv   = tid >> 6;
    const int lane = tid & 63;
    const int il   = lane & 15;
    const int hi   = lane >> 4;
    const int cb   = blockIdx.x * BN;

    {
        const int c4 = (tid & 15) * 4;
        const int k8 = tid >> 4;
        const bool ok = (cb + c4) < C_DIM;
        #pragma unroll
        for (int kk2 = 0; kk2 < 2; ++kk2) {
            const int kb = kk2 * 256 + k8 * 8;
            f32x4 v[8];
            #pragma unroll
            for (int j = 0; j < 8; ++j) {
                if (ok) v[j] = *(const f32x4*)(W + (size_t)(kb + j) * C_DIM + cb + c4);
                else    v[j] = (f32x4){0.f, 0.f, 0.f, 0.f};
            }
            const int q = kk2 * 32 + k8;
            #pragma unroll
            for (int cc = 0; cc < 4; ++cc) {
                const int c = c4 + cc;
                union { __hip_bfloat16 h[8]; bf16x8 b; } p;
                #pragma unroll
                for (int j = 0; j < 8; ++j) p.h[j] = __float2bfloat16(v[j][cc]);
                *(bf16x8*)&Bl[c * 512 + (q ^ (c & 7)) * 8] = p.b;
            }
        }
    }
    __syncthreads();

    f32acc acc[4][4];
    #pragma unroll
    for (int m = 0; m < 4; ++m)
        #pragma unroll
        for (int n = 0; n < 4; ++n)
            acc[m][n] = (f32acc){0.f, 0.f, 0.f, 0.f};

    int crow[4];
    #pragma unroll
    for (int m = 0; m < 4; ++m) crow[m] = (m * 16 + il) * 512;

    auto loadB = [&](bf16x8 (&bb)[4], int kt) {
        #pragma unroll
        for (int n = 0; n < 4; ++n)
            bb[n] = *(const bf16x8*)(xs2 + (size_t)((wv * 4 + n) * 64 + kt * 4 + hi) * 128 + il * 8);
    };
    auto step = [&](const bf16x8 (&bb)[4], int kt) {
        bf16x8 a[4];
        #pragma unroll
        for (int m = 0; m < 4; ++m) {
            const int c = m * 16 + il;
            const int q = (kt * 4 + hi) ^ (c & 7);
            a[m] = *(const bf16x8*)&Bl[crow[m] + q * 8];
        }
        #pragma unroll
        for (int m = 0; m < 4; ++m)
            #pragma unroll
            for (int n = 0; n < 4; ++n)
                acc[m][n] = __builtin_amdgcn_mfma_f32_16x16x32_bf16(a[m], bb[n], acc[m][n], 0, 0, 0);
    };

    bf16x8 b0[4], b1[4];
    loadB(b0, 0);
    #pragma unroll
    for (int kt = 0; kt < 16; kt += 2) {
        if (kt + 1 < 16) loadB(b1, kt + 1);
        step(b0, kt);
        if (kt + 2 < 16) loadB(b0, kt + 2);
        if (kt + 1 < 16) step(b1, kt + 1);
    }

    cf_epilogue(acc, wv, il, hi, cb, label, cosm, finl, tp[0], out);
}

extern "C" void kernel_launch(void* const* d_in, const int* in_sizes, int n_in,
                              void* d_out, int out_size, void* d_ws, size_t ws_size,
                              hipStream_t stream) {
    const float* x   = (const float*)d_in[0];
    const float* W   = (const float*)d_in[1];
    const int* label = (const int*)d_in[2];
    float* out = (float*)d_out;

    char* ws = (char*)d_ws;
    float* inv_norm = (float*)ws;          // 512 f32
    float* tl  = inv_norm + 512;
    float* cm  = tl + 512;
    float* fl  = cm + 512;
    float* tsc = fl + 512;
    __hip_bfloat16* xs2 = (__hip_bfloat16*)(ws + 16384);            // 512 KB
    __hip_bfloat16* Wt  = (__hip_bfloat16*)(ws + (1 << 20));        // 102.4 MB

    const size_t need = (size_t)(1 << 20) + (size_t)NPANEL * PANEL_ELEMS * sizeof(__hip_bfloat16);
    const bool big = (ws_size >= need);

    cf_knorm<<<DDIM, 256, 0, stream>>>(W, inv_norm);
    if (big) {
        cf_kconv<<<NPANEL, 512, 0, stream>>>(W, inv_norm, Wt);
        cf_kxs2<<<128, 256, 0, stream>>>(x, inv_norm, xs2, 0);   // norm folded into Wt
    } else {
        cf_kxs2<<<128, 256, 0, stream>>>(x, inv_norm, xs2, 1);   // norm folded into xs
    }
    cf_ktgt<<<NROW, 64, 0, stream>>>(x, W, inv_norm, label, tl, cm, fl);
    cf_kt<<<1, 512, 0, stream>>>(tl, tsc);

    if (big)
        cf_kgemm2<<<NPANEL, 512, 0, stream>>>(xs2, Wt, label, cm, fl, tsc, out);
    else
        cf_kgemm<<<NPANEL, 512, 0, stream>>>(xs2, W, label, cm, fl, tsc, out);
}

// Round 6
// 198.842 us; speedup vs baseline: 1.2179x; 1.2179x over previous
//
#include <hip/hip_runtime.h>
#include <hip/hip_bf16.h>

#define C_DIM 100000
#define NROW 512
#define DDIM 512
#define BN 64
#define NPANEL 1563          // ceil(C_DIM/64)
#define GRID_GEMM 512

typedef __attribute__((ext_vector_type(4))) float f32x4;
typedef __attribute__((ext_vector_type(8))) short bf16x8;
typedef __attribute__((ext_vector_type(4))) float f32acc;

// ---------------- kernel 1: inv row norms of W (norm over C per row d) ----------
__global__ __launch_bounds__(256) void cf_knorm(const float* __restrict__ W,
                                                float* __restrict__ inv_norm) {
    const int d = blockIdx.x;
    const float* row = W + (size_t)d * C_DIM;
    float s = 0.f;
    for (int c4 = threadIdx.x; c4 < C_DIM / 4; c4 += 256) {
        f32x4 v = *(const f32x4*)(row + c4 * 4);
        s += v.x * v.x + v.y * v.y + v.z * v.z + v.w * v.w;
    }
    #pragma unroll
    for (int off = 32; off; off >>= 1) s += __shfl_down(s, off, 64);
    __shared__ float wsum[4];
    if ((threadIdx.x & 63) == 0) wsum[threadIdx.x >> 6] = s;
    __syncthreads();
    if (threadIdx.x == 0) {
        float t = wsum[0] + wsum[1] + wsum[2] + wsum[3];
        inv_norm[d] = 1.0f / sqrtf(t);
    }
}

// ------- kernel 2: xs2 = bf16(x * inv_norm) in MFMA-fragment-tiled layout -------
// xs2[((row>>4)*64 + k8)*128 + (row&15)*8 + e]  (row=0..511, col=k8*8+e)
__global__ __launch_bounds__(256) void cf_kxs2(const float* __restrict__ x,
                                               const float* __restrict__ inv_norm,
                                               __hip_bfloat16* __restrict__ xs2) {
    const int idx = blockIdx.x * 256 + threadIdx.x;   // 0..32767
    const int row = idx >> 6;
    const int k8  = idx & 63;
    const float* xp = x + (size_t)row * DDIM + k8 * 8;
    f32x4 v0 = *(const f32x4*)(xp);
    f32x4 v1 = *(const f32x4*)(xp + 4);
    f32x4 s0 = *(const f32x4*)(inv_norm + k8 * 8);
    f32x4 s1 = *(const f32x4*)(inv_norm + k8 * 8 + 4);
    union { __hip_bfloat16 h[8]; bf16x8 v; } p;
    #pragma unroll
    for (int e = 0; e < 4; ++e) p.h[e]     = __float2bfloat16(v0[e] * s0[e]);
    #pragma unroll
    for (int e = 0; e < 4; ++e) p.h[4 + e] = __float2bfloat16(v1[e] * s1[e]);
    *(bf16x8*)(xs2 + ((size_t)((row >> 4) * 64 + k8) * 128 + (row & 15) * 8)) = p.v;
}

// ---------------- kernel 3: target logits, cos_m, final -------------------------
__global__ __launch_bounds__(64) void cf_ktgt(const float* __restrict__ x,
                                              const float* __restrict__ W,
                                              const float* __restrict__ inv_norm,
                                              const int* __restrict__ label,
                                              float* __restrict__ tl,
                                              float* __restrict__ cm,
                                              float* __restrict__ fl) {
    const int i = blockIdx.x;
    const int lane = threadIdx.x;
    const int lab = label[i];
    float s = 0.f;
    for (int d = lane; d < DDIM; d += 64)
        s += x[(size_t)i * DDIM + d] * inv_norm[d] * W[(size_t)d * C_DIM + lab];
    #pragma unroll
    for (int off = 32; off; off >>= 1) s += __shfl_down(s, off, 64);
    if (lane == 0) {
        float t = fminf(fmaxf(s, -1.f), 1.f);
        float sn = sqrtf(fmaxf(1.f - t * t, 0.f));
        float c = t * 0.8775825618903728f - sn * 0.479425538604203f; // cos(th+m)
        tl[i] = t;
        cm[i] = c;
        fl[i] = (t > -0.8775825618903728f) ? c : (t - 0.2397127693021015f);
    }
}

// ---------------- kernel 4: t = 0.01 * mean(target_logit) -----------------------
__global__ __launch_bounds__(512) void cf_kt(const float* __restrict__ tl,
                                             float* __restrict__ tout) {
    float s = tl[threadIdx.x];
    #pragma unroll
    for (int off = 32; off; off >>= 1) s += __shfl_down(s, off, 64);
    __shared__ float w[8];
    if ((threadIdx.x & 63) == 0) w[threadIdx.x >> 6] = s;
    __syncthreads();
    if (threadIdx.x == 0) {
        float tt = 0.f;
        #pragma unroll
        for (int j = 0; j < 8; ++j) tt += w[j];
        tout[0] = 0.01f * (tt / 512.0f);
    }
}

// ---------------- kernel 5: persistent GEMM + fused epilogue --------------------
// 512 persistent blocks; block b owns panels b, b+512, b+1024[, b+1536].
// LDS = 2 half-panel buffers (64 cols x 256 k bf16 = 32 KB each, XOR-swizzled).
// Per half s: compute 8 kt from buf[s&1] while half s+1's W loads (issued last
// iteration) stream from HBM; then cvt+ds_write s+1, issue s+2's loads, raw
// s_barrier + lgkmcnt(0) (NO vmcnt drain -> loads stay in flight across it).
__global__ __launch_bounds__(512, 2) void cf_kgemm3(
    const __hip_bfloat16* __restrict__ xs2,
    const float* __restrict__ W,
    const int* __restrict__ label,
    const float* __restrict__ cosm,
    const float* __restrict__ finl,
    const float* __restrict__ tp,
    float* __restrict__ out) {
    __shared__ __attribute__((aligned(16))) __hip_bfloat16 Bl[2][64 * 256];

    const int tid  = threadIdx.x;
    const int wv   = tid >> 6;       // 0..7
    const int lane = tid & 63;
    const int il   = lane & 15;
    const int hi   = lane >> 4;

    // staging decomposition: thread = col-quad c4 x k-octet k8
    const int c4 = (tid & 15) * 4;   // 0..60
    const int k8 = tid >> 4;         // 0..31 (covers 256 k per half)

    const int bid = blockIdx.x;
    const int np  = (NPANEL - bid + GRID_GEMM - 1) / GRID_GEMM;  // 3 or 4
    const int nS  = 2 * np;

    f32x4 sv[8];   // in-flight W stage registers (one half)

    auto stageIssue = [&](int s) {
        const int p  = bid + (s >> 1) * GRID_GEMM;
        const int cb = p * BN;
        const int h  = s & 1;
        const bool ok = (cb + c4) < C_DIM;   // C_DIM%4==0 -> quad all-or-nothing
        const float* wp = W + (size_t)(h * 256 + k8 * 8) * C_DIM + cb + c4;
        #pragma unroll
        for (int j = 0; j < 8; ++j) {
            if (ok) sv[j] = *(const f32x4*)(wp + (size_t)j * C_DIM);
            else    sv[j] = (f32x4){0.f, 0.f, 0.f, 0.f};
        }
    };
    auto stageCommit = [&](int buf) {
        #pragma unroll
        for (int cc = 0; cc < 4; ++cc) {
            const int c = c4 + cc;
            union { __hip_bfloat16 h8[8]; bf16x8 b; } pk;
            #pragma unroll
            for (int j = 0; j < 8; ++j) pk.h8[j] = __float2bfloat16(sv[j][cc]);
            *(bf16x8*)&Bl[buf][c * 256 + ((k8 ^ (c & 7)) * 8)] = pk.b;
        }
    };

    f32acc acc[4][4];
    #pragma unroll
    for (int m = 0; m < 4; ++m)
        #pragma unroll
        for (int n = 0; n < 4; ++n)
            acc[m][n] = (f32acc){0.f, 0.f, 0.f, 0.f};

    auto loadB = [&](bf16x8 (&bb)[4], int ktA) {   // ktA = 0..15 (panel-abs kt)
        #pragma unroll
        for (int n = 0; n < 4; ++n)
            bb[n] = *(const bf16x8*)(xs2 + (size_t)((wv * 4 + n) * 64 + ktA * 4 + hi) * 128 + il * 8);
    };
    auto step = [&](int buf, const bf16x8 (&bb)[4], int ktl) {   // ktl = 0..7
        bf16x8 a[4];
        #pragma unroll
        for (int m = 0; m < 4; ++m) {
            const int c = m * 16 + il;
            a[m] = *(const bf16x8*)&Bl[buf][c * 256 + (((ktl * 4 + hi) ^ (c & 7)) * 8)];
        }
        #pragma unroll
        for (int m = 0; m < 4; ++m)
            #pragma unroll
            for (int n = 0; n < 4; ++n)
                acc[m][n] = __builtin_amdgcn_mfma_f32_16x16x32_bf16(a[m], bb[n], acc[m][n], 0, 0, 0);
    };

#define HSYNC do { asm volatile("s_waitcnt lgkmcnt(0)" ::: "memory"); \
                   __builtin_amdgcn_s_barrier(); \
                   __builtin_amdgcn_sched_barrier(0); } while (0)

    // prologue: commit half 0, leave half 1's loads in flight
    stageIssue(0);
    stageCommit(0);
    stageIssue(1);
    HSYNC;

    const float t = tp[0];
    const int ib = wv * 64;

    for (int s = 0; s < nS; ++s) {
        const int buf = s & 1;
        const int h   = s & 1;
        const int kb  = h * 8;

        bf16x8 b0_[4], b1_[4];
        loadB(b0_, kb);
        #pragma unroll
        for (int ktl = 0; ktl < 8; ktl += 2) {
            if (ktl + 1 < 8) loadB(b1_, kb + ktl + 1);
            step(buf, b0_, ktl);
            if (ktl + 2 < 8) loadB(b0_, kb + ktl + 2);
            step(buf, b1_, ktl + 1);
        }

        if (h == 1) {
            // panel complete: fused curricular epilogue, then reset acc
            const int cb = (bid + (s >> 1) * GRID_GEMM) * BN;
            #pragma unroll
            for (int n = 0; n < 4; ++n) {
                const int i = ib + n * 16 + il;
                const float cmv = cosm[i];
                const float flv = finl[i];
                const int lab = label[i];
                float* orow = out + (size_t)i * C_DIM;
                #pragma unroll
                for (int m = 0; m < 4; ++m) {
                    const int c0 = cb + m * 16 + hi * 4;
                    if (c0 < C_DIM) {
                        f32x4 v = acc[m][n];
                        f32x4 o;
                        #pragma unroll
                        for (int r = 0; r < 4; ++r) {
                            float cz = fminf(fmaxf(v[r], -1.f), 1.f);
                            float ov = (cz > cmv) ? cz * (t + cz) : cz;
                            if (c0 + r == lab) ov = flv;
                            o[r] = ov * 64.0f;
                        }
                        *(f32x4*)(orow + c0) = o;
                    }
                }
            }
            #pragma unroll
            for (int m = 0; m < 4; ++m)
                #pragma unroll
                for (int n = 0; n < 4; ++n)
                    acc[m][n] = (f32acc){0.f, 0.f, 0.f, 0.f};
        }

        if (s + 1 < nS) {
            stageCommit(buf ^ 1);                // waits (counted) on sv loads
            if (s + 2 < nS) stageIssue(s + 2);   // next half's HBM stream starts
            HSYNC;
        }
    }
#undef HSYNC
}

extern "C" void kernel_launch(void* const* d_in, const int* in_sizes, int n_in,
                              void* d_out, int out_size, void* d_ws, size_t ws_size,
                              hipStream_t stream) {
    const float* x   = (const float*)d_in[0];
    const float* W   = (const float*)d_in[1];
    const int* label = (const int*)d_in[2];
    float* out = (float*)d_out;

    char* ws = (char*)d_ws;
    float* inv_norm = (float*)ws;          // 512 f32
    float* tl  = inv_norm + 512;
    float* cm  = tl + 512;
    float* fl  = cm + 512;
    float* tsc = fl + 512;
    __hip_bfloat16* xs2 = (__hip_bfloat16*)(ws + 16384);  // 512*512 bf16 = 512KB

    cf_knorm<<<DDIM, 256, 0, stream>>>(W, inv_norm);
    cf_kxs2<<<128, 256, 0, stream>>>(x, inv_norm, xs2);
    cf_ktgt<<<NROW, 64, 0, stream>>>(x, W, inv_norm, label, tl, cm, fl);
    cf_kt<<<1, 512, 0, stream>>>(tl, tsc);

    cf_kgemm3<<<GRID_GEMM, 512, 0, stream>>>(xs2, W, label, cm, fl, tsc, out);
}